// Round 13
// baseline (127.766 us; speedup 1.0000x reference)
//
#include <hip/hip_runtime.h>

typedef unsigned long long u64;
typedef unsigned int u32;

#define BDIM 16
#define NP   4096
#define NC   91
#define NCM1 90
#define MSEL 4096       // top-M per image (reference M)
#define NSORT 1024      // batch-0 sorted prefix size
#define KOUT 100
#define RSLOT 19        // max candidates per row (scores sum to 1, >0.05 => <=19)
#define CAP_D (NP * RSLOT)   // 77824: provable per-image max -> no overflow possible
#define SCORE_T 0.05f
#define NMS_T   0.5f
#define OFFSETF 10000.0f
#define DW_CLAMP_F 4.135166556742356f
#define WF 1333.0f
#define HF 800.0f

#define TN 1024
#define NW (TN / 64)      // 16 waves
#define RPB 64            // rows per k_soft block (64 blocks per image)
#define AMAX (KOUT + 64)  // accepted-list capacity (last chunk may overshoot cap check)

// ---------------- Kernel 0: zero the 16 per-image counters ----------------
__global__ __launch_bounds__(64) void k_zero(int* __restrict__ gcount) {
    if (threadIdx.x < BDIM) gcount[threadIdx.x] = 0;
}

// ---------------- Kernel 1: softmax -> dense candidates (round-10/12 verified) ----------------
__global__ __launch_bounds__(256) void k_soft(const float* __restrict__ logits,
                                              u64* __restrict__ dense,
                                              int* __restrict__ gcount) {
    __shared__ u64 stage[RPB * RSLOT];   // 1216 keys max (block's provable cap) = 9.5 KB
    __shared__ int s_cnt, s_base;

    int blk  = blockIdx.x;               // 1024 blocks; 64 consecutive rows each
    int b    = blk >> 6;                 // image index (64 blocks per image)
    int lane = threadIdx.x & 63;
    int wid  = threadIdx.x >> 6;

    if (threadIdx.x == 0) s_cnt = 0;
    __syncthreads();

    u64 lm = (1ull << lane) - 1ull;
    for (int it = 0; it < RPB / 4; ++it) {
        int row = blk * RPB + it * 4 + wid;          // one wave per row
        const float* lg = logits + (long)row * NC;

        float v0 = lg[lane];
        float v1 = (lane < NC - 64) ? lg[64 + lane] : -3.0e38f;
        float mx = fmaxf(v0, v1);
#pragma unroll
        for (int s = 32; s; s >>= 1) mx = fmaxf(mx, __shfl_xor(mx, s));
        float e0 = expf(v0 - mx);
        float e1 = (lane < NC - 64) ? expf(v1 - mx) : 0.0f;
        float sum = e0 + e1;
#pragma unroll
        for (int s = 32; s; s >>= 1) sum += __shfl_xor(sum, s);

        float s0 = e0 / sum;
        float s1 = e1 / sum;

        int n = row & (NP - 1);
        bool p0 = (lane >= 1) && (s0 > SCORE_T);          // class = lane (skip background 0)
        bool p1 = (lane < NC - 64) && (s1 > SCORE_T);     // class = 64 + lane
        u64 m0 = __ballot(p0);
        u64 m1 = __ballot(p1);
        int c0  = __popcll(m0);
        int cnt = c0 + __popcll(m1);

        int base = 0;
        if (lane == 0 && cnt) base = atomicAdd(&s_cnt, cnt);   // LDS atomic, 1/wave/row
        base = __shfl(base, 0);
        if (p0) {
            int pos  = base + __popcll(m0 & lm);
            int flat = n * NCM1 + (lane - 1);
            stage[pos] = ((u64)__float_as_uint(s0) << 32) | (u32)(~(u32)flat);
        }
        if (p1) {
            int pos  = base + c0 + __popcll(m1 & lm);
            int flat = n * NCM1 + (64 + lane - 1);
            stage[pos] = ((u64)__float_as_uint(s1) << 32) | (u32)(~(u32)flat);
        }
    }
    __syncthreads();

    if (threadIdx.x == 0) s_base = atomicAdd(&gcount[b], s_cnt);  // 64 atomics/image total
    __syncthreads();
    int m = s_cnt, base = s_base;
    u64* kb = dense + (long)b * CAP_D + base;        // base+m <= 77824 = CAP_D provably
    for (int i = threadIdx.x; i < m; i += 256) kb[i] = stage[i];
}

// ---------------- Kernel 2: dual-rank radix select over dense (round-8/10/12 verified) ----------------
__global__ __launch_bounds__(1024) void k_select(const u64* __restrict__ dense,
                                                 const int* __restrict__ nsel,
                                                 u64* __restrict__ Tsel,
                                                 u64* __restrict__ Tsel2) {
    __shared__ int hist[2048];
    __shared__ int s_sel, s_gt;
    int blk = blockIdx.x;
    int b   = blk & (BDIM - 1);
    int rank = (blk < BDIM) ? MSEL : NSORT;
    u64* dst = (blk < BDIM) ? (Tsel + b) : (Tsel2 + b);
    int tid = threadIdx.x;
    int n = nsel[b]; if (n > CAP_D) n = CAP_D;
    if (n <= rank) { if (tid == 0) *dst = 0ull; return; }

    const u64* kb = dense + (long)b * CAP_D;
    u64 prefix = 0, mask = 0;
    const int shifts[6] = {53, 42, 31, 20, 10, 0};
    const int bitsv [6] = {11, 11, 11, 11, 10, 10};

    for (int pass = 0; pass < 6; ++pass) {
        int shift = shifts[pass];
        int nb = 1 << bitsv[pass];
        if (tid < nb) hist[tid] = 0;
        if (tid + 1024 < nb) hist[tid + 1024] = 0;
        __syncthreads();
        for (int i = tid; i < n; i += 1024) {
            u64 k = kb[i];
            if ((k & mask) == prefix)
                atomicAdd(&hist[(int)((k >> shift) & (u64)(nb - 1))], 1);
        }
        __syncthreads();
        for (int d = 1; d < nb; d <<= 1) {
            int v0 = 0, v1 = 0;
            if (tid < nb && tid + d < nb) v0 = hist[tid + d];
            if (tid + 1024 < nb && tid + 1024 + d < nb) v1 = hist[tid + 1024 + d];
            __syncthreads();
            if (tid < nb) hist[tid] += v0;
            if (tid + 1024 < nb) hist[tid + 1024] += v1;
            __syncthreads();
        }
        for (int j = tid; j < nb; j += 1024) {
            int c  = hist[j];
            int cn = (j + 1 < nb) ? hist[j + 1] : 0;
            if (c >= rank && cn < rank) { s_sel = j; s_gt = cn; }
        }
        __syncthreads();
        prefix |= ((u64)s_sel) << shift;
        mask   |= ((u64)(nb - 1)) << shift;
        rank   -= s_gt;
        __syncthreads();
    }
    if (tid == 0) *dst = prefix;
}

// ---------------- Kernel 3: gather + sort + decode + CHUNK-PARALLEL walk NMS ----------------
__global__ __launch_bounds__(TN) void k_nms(const u64* __restrict__ dense,
                                            const int* __restrict__ nsel,
                                            const u64* __restrict__ Tsel,
                                            const u64* __restrict__ Tsel2,
                                            const float* __restrict__ boxreg,
                                            const float* __restrict__ props,
                                            float* __restrict__ out) {
    __shared__ u64 skey[MSEL];          // 32 KB keys (sorted desc per batch)
    __shared__ float4 sbox[MSEL];       // 64 KB raw clipped boxes
    __shared__ float2 spack[MSEL];      // 32 KB {offset-area, (float)label}
    __shared__ float4 cboxS[64];        // chunk scratch (walk wave only)
    __shared__ float2 cpackS[64];
    __shared__ float aX1[AMAX], aY1[AMAX], aX2[AMAX], aY2[AMAX], aArea[AMAX], aLab[AMAX];
    __shared__ u64 aKey[AMAX];
    __shared__ int s_cnt, s_nacc;

    int b = blockIdx.x, tid = threadIdx.x;
    int lane = tid & 63, wid = tid >> 6;
    int n = nsel[b]; if (n > CAP_D) n = CAP_D;
    u64 T  = Tsel[b];
    u64 T2 = Tsel2[b];
    const u64* kb = dense + (long)b * CAP_D;
    u64 lm = (1ull << lane) - 1ull;
    int npad = (n + TN - 1) & ~(TN - 1);

    int nacc = 0;                        // live in wave-0 registers across batches

    for (int bt = 0; bt < 2; ++bt) {
        if (bt == 1) {
            if (s_nacc >= KOUT || T2 == 0ull) break;   // uniform (post-barrier)
        }
        int SZ = bt ? MSEL : NSORT;

        // ---- zero + wave-aggregated flat gather (round-8/12 verified) ----
        for (int i = tid; i < SZ; i += TN) skey[i] = 0ull;
        if (tid == 0) s_cnt = 0;
        __syncthreads();
        for (int i0 = tid; i0 < npad; i0 += TN) {
            bool inb = (i0 < n);
            u64 k = inb ? kb[i0] : 0ull;
            bool pred = inb && (bt == 0 ? (k >= T2) : (k >= T && k < T2));
            u64 mb_ = __ballot(pred);
            int cnt = __popcll(mb_);
            int bp = 0;
            if (lane == 0 && cnt) bp = atomicAdd(&s_cnt, cnt);
            bp = __shfl(bp, 0);
            if (pred) {
                int pos = bp + __popcll(mb_ & lm);
                if (pos < SZ) skey[pos] = k;
            }
        }
        __syncthreads();
        int mb = s_cnt; if (mb > SZ) mb = SZ;

        // ---- sort descending (zeros sink to end) ----
        if (bt == 0) {
            // register bitonic, 1 element/thread; shfl for j<64, LDS for j>=64 (round-8 verified)
            u64 r = skey[tid];
            for (int kk = 2; kk <= NSORT; kk <<= 1) {
                for (int j = kk >> 1; j; j >>= 1) {
                    u64 p;
                    if (j >= 64) {
                        skey[tid] = r;
                        __syncthreads();
                        p = skey[tid ^ j];
                        __syncthreads();
                    } else {
                        p = __shfl_xor(r, j);
                    }
                    bool lower = (tid & j) == 0;
                    bool desc  = ((tid & kk) == 0);
                    u64 mx = (r > p) ? r : p;
                    u64 mn = (r > p) ? p : r;
                    r = (lower == desc) ? mx : mn;
                }
            }
            skey[tid] = r;
            __syncthreads();
        } else {
            // LDS bitonic over MSEL (round-7 verified)
            for (int kk = 2; kk <= MSEL; kk <<= 1) {
                for (int j = kk >> 1; j > 0; j >>= 1) {
                    for (int t = tid; t < MSEL; t += TN) {
                        int l = t ^ j;
                        if (l > t) {
                            u64 a = skey[t], c = skey[l];
                            bool up = ((t & kk) == 0);
                            bool sw = up ? (a < c) : (a > c);
                            if (sw) { skey[t] = c; skey[l] = a; }
                        }
                    }
                    __syncthreads();
                }
            }
        }

        // ---- decode sorted candidates (round-6/7/8/12 verified expressions) ----
        for (int i = tid; i < mb; i += TN) {
            u64 k = skey[i];
            int flat = (int)(~(u32)k);
            int nidx = flat / NCM1;
            int c    = flat - nidx * NCM1 + 1;
            const float* pr = props + ((long)b * NP + nidx) * 4;
            float x1 = pr[0], y1 = pr[1], x2 = pr[2], y2 = pr[3];
            float w = x2 - x1, h = y2 - y1;
            float cx = x1 + 0.5f * w, cy = y1 + 0.5f * h;
            const float* rr = boxreg + (((long)b * NP + nidx) * NC + c) * 4;
            float dx = rr[0] / 10.0f, dy = rr[1] / 10.0f;
            float dw = fminf(rr[2] / 5.0f, DW_CLAMP_F);
            float dh = fminf(rr[3] / 5.0f, DW_CLAMP_F);
            // avoid FMA contraction: numpy does separate mul + add
            float pcx = __fadd_rn(__fmul_rn(dx, w), cx);
            float pcy = __fadd_rn(__fmul_rn(dy, h), cy);
            float pw  = __fmul_rn(expf(dw), w);
            float ph2 = __fmul_rn(expf(dh), h);
            float bx1 = fminf(fmaxf(pcx - 0.5f * pw, 0.0f), WF);
            float by1 = fminf(fmaxf(pcy - 0.5f * ph2, 0.0f), HF);
            float bx2 = fminf(fmaxf(pcx + 0.5f * pw, 0.0f), WF);
            float by2 = fminf(fmaxf(pcy + 0.5f * ph2, 0.0f), HF);
            sbox[i] = make_float4(bx1, by1, bx2, by2);
            // area on class-offset coords, exactly as reference computes it
            float offB = (float)c * OFFSETF;
            float ox1 = bx1 + offB, oy1 = by1 + offB;
            float ox2 = bx2 + offB, oy2 = by2 + offB;
            spack[i] = make_float2((ox2 - ox1) * (oy2 - oy1), (float)c);
        }
        __syncthreads();

        // ---- chunk-parallel walk (wave 0 only; no block barriers) ----
        // Greedy equivalence: candidate accepted iff no earlier-ACCEPTED same-class
        // box has IoU > NMS_T. deadmask = conflicts vs prior-chunk accepted;
        // rowm = within-chunk pairwise conflicts (fminf/fmaxf/fadd commutative ->
        // bit-identical to reference's selected/tested operand roles);
        // serial bit-sweep in index order = exact greedy acceptance sequence.
        if (wid == 0) {
            for (int c0 = 0; c0 < mb && nacc < KOUT; c0 += 64) {
                int i = c0 + lane;
                bool valid = (i < mb);
                float4 Bv = valid ? sbox[i] : make_float4(0.f, 0.f, 0.f, 0.f);
                float2 pk = valid ? spack[i] : make_float2(0.f, -1.f);
                float areaB = pk.x, labf = pk.y;
                float off = __fmul_rn(labf, OFFSETF);
                cboxS[lane] = Bv;
                cpackS[lane] = pk;
                __builtin_amdgcn_wave_barrier();

                // step 1: conflict vs accepted list (broadcast reads, parallel lanes)
                bool conf = false;
                for (int a = 0; a < nacc; ++a) {
                    if (aLab[a] == labf) {
                        float op1x = __fadd_rn(fminf(aX2[a], Bv.z), off);
                        float op2x = __fadd_rn(fmaxf(aX1[a], Bv.x), off);
                        float iw = fmaxf(op1x - op2x, 0.0f);
                        float op1y = __fadd_rn(fminf(aY2[a], Bv.w), off);
                        float op2y = __fadd_rn(fmaxf(aY1[a], Bv.y), off);
                        float ih = fmaxf(op1y - op2y, 0.0f);
                        float inter = iw * ih;
                        float denom = areaB + aArea[a] - inter + 1e-9f;
                        if (inter / denom > NMS_T) conf = true;
                    }
                }
                u64 validmask = __ballot(valid);
                u64 deadmask  = __ballot(conf);

                // step 2: within-chunk pairwise conflict row (parallel lanes)
                u64 rowm = 0;
                for (int t = 0; t < 64; ++t) {
                    if (t != lane) {
                        float2 tp = cpackS[t];
                        if (tp.y == labf) {
                            float4 Tv = cboxS[t];
                            float op1x = __fadd_rn(fminf(Tv.z, Bv.z), off);
                            float op2x = __fadd_rn(fmaxf(Tv.x, Bv.x), off);
                            float iw = fmaxf(op1x - op2x, 0.0f);
                            float op1y = __fadd_rn(fminf(Tv.w, Bv.w), off);
                            float op2y = __fadd_rn(fmaxf(Tv.y, Bv.y), off);
                            float ih = fmaxf(op1y - op2y, 0.0f);
                            float inter = iw * ih;
                            float denom = areaB + tp.x - inter + 1e-9f;
                            if (inter / denom > NMS_T) rowm |= (1ull << t);
                        }
                    }
                }

                // step 3: serial scalar sweep (uniform; no ballots, no LDS)
                u64 alive = validmask & ~deadmask;
                u64 acc = 0;
                int room = KOUT - nacc;
                while (alive && room) {
                    int j = __builtin_ctzll(alive);
                    acc |= (1ull << j);
                    --room;
                    u64 rj = __shfl(rowm, j);       // accepted j's conflict row
                    alive &= ~rj;
                    alive &= ~(1ull << j);
                }

                // append accepted (order = ascending j = descending score)
                if (acc & (1ull << lane)) {
                    int idx = nacc + __popcll(acc & lm);
                    aX1[idx] = Bv.x; aY1[idx] = Bv.y; aX2[idx] = Bv.z; aY2[idx] = Bv.w;
                    aArea[idx] = areaB; aLab[idx] = labf;
                    aKey[idx] = skey[i];
                }
                __builtin_amdgcn_wave_barrier();
                nacc += __popcll(acc);
            }
            if (lane == 0) s_nacc = nacc;
        }
        __syncthreads();
    }

    // ---- emit outputs in acceptance order ----
    int na = s_nacc; if (na > KOUT) na = KOUT;
    for (int a = tid; a < KOUT; a += TN) {
        float* ob = out + ((long)b * KOUT + a) * 4;
        if (a < na) {
            ob[0] = aX1[a]; ob[1] = aY1[a]; ob[2] = aX2[a]; ob[3] = aY2[a];
            out[BDIM * KOUT * 4 + b * KOUT + a] = __uint_as_float((u32)(aKey[a] >> 32));
            out[BDIM * KOUT * 5 + b * KOUT + a] = aLab[a];
            out[BDIM * KOUT * 6 + b * KOUT + a] = 1.0f;
        } else {
            ob[0] = 0.0f; ob[1] = 0.0f; ob[2] = 0.0f; ob[3] = 0.0f;
            out[BDIM * KOUT * 4 + b * KOUT + a] = 0.0f;
            out[BDIM * KOUT * 5 + b * KOUT + a] = -1.0f;
            out[BDIM * KOUT * 6 + b * KOUT + a] = 0.0f;
        }
    }
}

extern "C" void kernel_launch(void* const* d_in, const int* in_sizes, int n_in,
                              void* d_out, int out_size, void* d_ws, size_t ws_size,
                              hipStream_t stream) {
    const float* logits = (const float*)d_in[0];
    const float* boxreg = (const float*)d_in[1];
    const float* props  = (const float*)d_in[2];
    float* out = (float*)d_out;

    char* ws = (char*)d_ws;
    int* gcount = (int*)(ws + 0);                 // 64 B
    u64* Tsel   = (u64*)(ws + 256);               // 128 B
    u64* Tsel2  = (u64*)(ws + 512);               // 128 B
    u64* dense  = (u64*)(ws + 1024);              // 16*77824*8 = 9.96 MB

    k_zero<<<1, 64, 0, stream>>>(gcount);
    k_soft<<<(BDIM * NP) / RPB, 256, 0, stream>>>(logits, dense, gcount);
    k_select<<<2 * BDIM, 1024, 0, stream>>>(dense, gcount, Tsel, Tsel2);
    k_nms<<<BDIM, TN, 0, stream>>>(dense, gcount, Tsel, Tsel2, boxreg, props, out);
}